// Round 1
// baseline (1132.582 us; speedup 1.0000x reference)
//
#include <hip/hip_runtime.h>

// Problem constants
static constexpr int kBS    = 8;
static constexpr int kNROI  = 128;
static constexpr int kR     = kBS * kNROI;   // 1024 rows
static constexpr int kCH    = 1280;
static constexpr int kH     = 64;
static constexpr int kW     = 64;
static constexpr int kPIX   = kH * kW;       // 4096
static constexpr int kINNER = 5120;
static constexpr int kOUTC  = 1024;
static constexpr int kXE    = 2 * kOUTC;     // 2048 concat width

// ---------------------------------------------------------------------------
// Transpose z: (b, c, H, W) -> zt: (b, H*W, c)   [channels-last for gather]
// ---------------------------------------------------------------------------
__global__ __launch_bounds__(256) void transpose_z(const float* __restrict__ z,
                                                   float* __restrict__ zt) {
    __shared__ float tile[32][33];
    const int b  = blockIdx.z;
    const int p0 = blockIdx.x * 32;   // pixel tile
    const int c0 = blockIdx.y * 32;   // channel tile
    const float* zb  = z  + (size_t)b * kCH * kPIX;
    float*       ztb = zt + (size_t)b * kPIX * kCH;
    const int tx = threadIdx.x;       // 0..31
    const int ty = threadIdx.y;       // 0..7
#pragma unroll
    for (int i = 0; i < 4; ++i) {
        const int c = c0 + ty + i * 8;
        tile[ty + i * 8][tx] = zb[(size_t)c * kPIX + p0 + tx];
    }
    __syncthreads();
#pragma unroll
    for (int i = 0; i < 4; ++i) {
        const int p = p0 + ty + i * 8;
        ztb[(size_t)p * kCH + c0 + tx] = tile[tx][ty + i * 8];
    }
}

// ---------------------------------------------------------------------------
// ROI-align 1x1 with separable point weights.
// One block per ROI (256 threads). Thread 0 builds the <=16-entry Y and X
// point lists (index + combined mask*bilinear weight), then all threads
// gather float4 channel chunks.
// ---------------------------------------------------------------------------
struct RoiLists {
    int   yidx[16], xidx[16];
    float ywt[16], xwt[16];
    int   ny, nx;
    float invCount;
};

__device__ inline void build_lists(const float* __restrict__ bboxes, int r, RoiLists* L) {
    const float x1 = bboxes[r * 4 + 0] * 0.125f - 0.5f;
    const float y1 = bboxes[r * 4 + 1] * 0.125f - 0.5f;
    const float x2 = bboxes[r * 4 + 2] * 0.125f - 0.5f;
    const float y2 = bboxes[r * 4 + 3] * 0.125f - 0.5f;
    const float rw = x2 - x1, rh = y2 - y1;
    const float gwf = fminf(fmaxf(ceilf(rw), 1.0f), 8.0f);
    const float ghf = fminf(fmaxf(ceilf(rh), 1.0f), 8.0f);
    const int gw = (int)gwf, gh = (int)ghf;
    L->invCount = 1.0f / (gwf * ghf);
    for (int g = 0; g < gh; ++g) {
        const float c   = y1 + ((float)g + 0.5f) * rh / ghf;
        const bool oob  = (c < -1.0f) || (c > 64.0f);
        const float cc  = fmaxf(c, 0.0f);
        const float lo0 = floorf(cc);
        const bool hic  = (lo0 >= 63.0f);
        const int lo    = (int)fminf(lo0, 63.0f);
        const int hi    = (int)fminf(lo0 + 1.0f, 63.0f);
        const float fr  = hic ? 0.0f : (cc - lo0);
        const float m   = oob ? 0.0f : 1.0f;
        L->yidx[2 * g]     = lo; L->ywt[2 * g]     = m * (1.0f - fr);
        L->yidx[2 * g + 1] = hi; L->ywt[2 * g + 1] = m * fr;
    }
    L->ny = 2 * gh;
    for (int g = 0; g < gw; ++g) {
        const float c   = x1 + ((float)g + 0.5f) * rw / gwf;
        const bool oob  = (c < -1.0f) || (c > 64.0f);
        const float cc  = fmaxf(c, 0.0f);
        const float lo0 = floorf(cc);
        const bool hic  = (lo0 >= 63.0f);
        const int lo    = (int)fminf(lo0, 63.0f);
        const int hi    = (int)fminf(lo0 + 1.0f, 63.0f);
        const float fr  = hic ? 0.0f : (cc - lo0);
        const float m   = oob ? 0.0f : 1.0f;
        L->xidx[2 * g]     = lo; L->xwt[2 * g]     = m * (1.0f - fr);
        L->xidx[2 * g + 1] = hi; L->xwt[2 * g + 1] = m * fr;
    }
    L->nx = 2 * gw;
}

// Gather from channels-last zt (fast path)
__global__ __launch_bounds__(256) void roi_gather_t(const float* __restrict__ zt,
                                                    const float* __restrict__ bboxes,
                                                    float* __restrict__ x) {
    const int r = blockIdx.x;
    const int b = r >> 7;
    __shared__ RoiLists L;
    if (threadIdx.x == 0) build_lists(bboxes, r, &L);
    __syncthreads();
    const int ny = L.ny, nx = L.nx;
    const float ic = L.invCount;
    const float* ztb = zt + (size_t)b * kPIX * kCH;
    for (int c4 = threadIdx.x; c4 < kCH / 4; c4 += 256) {
        float ax = 0.f, ay = 0.f, az = 0.f, aw = 0.f;
        for (int iy = 0; iy < ny; ++iy) {
            const float wy = L.ywt[iy];
            const int   Y  = L.yidx[iy];
            for (int ix = 0; ix < nx; ++ix) {
                const float w = wy * L.xwt[ix];
                const float4 v =
                    *(const float4*)(ztb + ((size_t)(Y * kW + L.xidx[ix])) * kCH + c4 * 4);
                ax += w * v.x; ay += w * v.y; az += w * v.z; aw += w * v.w;
            }
        }
        float4 o; o.x = ax * ic; o.y = ay * ic; o.z = az * ic; o.w = aw * ic;
        *(float4*)(x + (size_t)r * kCH + c4 * 4) = o;
    }
}

// Gather directly from z (b,c,H,W) (fallback if workspace too small)
__global__ __launch_bounds__(256) void roi_gather_direct(const float* __restrict__ z,
                                                         const float* __restrict__ bboxes,
                                                         float* __restrict__ x) {
    const int r = blockIdx.x;
    const int b = r >> 7;
    __shared__ RoiLists L;
    if (threadIdx.x == 0) build_lists(bboxes, r, &L);
    __syncthreads();
    const int ny = L.ny, nx = L.nx;
    const float ic = L.invCount;
    const float* zb = z + (size_t)b * kCH * kPIX;
    for (int c = threadIdx.x; c < kCH; c += 256) {
        const float* zc = zb + (size_t)c * kPIX;
        float acc = 0.f;
        for (int iy = 0; iy < ny; ++iy) {
            const float wy = L.ywt[iy];
            const int base = L.yidx[iy] * kW;
            for (int ix = 0; ix < nx; ++ix)
                acc += wy * L.xwt[ix] * zc[base + L.xidx[ix]];
        }
        x[(size_t)r * kCH + c] = acc * ic;
    }
}

// ---------------------------------------------------------------------------
// Tiled fp32 GEMM: C(MxN) = op(A(MxK) @ B(KxN) + bias), optional relu.
// 64x64 tile, BK=16, 256 threads, 4x4 per thread. All dims multiples of 64/16.
// ---------------------------------------------------------------------------
template <bool RELU>
__global__ __launch_bounds__(256) void gemm_f32(const float* __restrict__ A,
                                                const float* __restrict__ B,
                                                const float* __restrict__ bias,
                                                float* __restrict__ C,
                                                int K, int lda, int ldb, int ldc) {
    __shared__ float As[16][64];
    __shared__ float Bs[16][64];
    const int t  = threadIdx.x;
    const int tx = t & 15, ty = t >> 4;
    const int m0 = blockIdx.y * 64, n0 = blockIdx.x * 64;

    const int am = t >> 2;            // 0..63 row within A tile
    const int ak = (t & 3) * 4;       // 0,4,8,12
    const int bk = t >> 4;            // 0..15 row within B tile
    const int bn = (t & 15) * 4;      // 0..60

    const float* Aptr = A + (size_t)(m0 + am) * lda + ak;
    const float* Bptr = B + (size_t)bk * ldb + n0 + bn;

    float acc[4][4] = {};

    for (int k0 = 0; k0 < K; k0 += 16) {
        const float4 av = *(const float4*)(Aptr + k0);
        const float4 bv = *(const float4*)(Bptr + (size_t)k0 * ldb);
        __syncthreads();
        As[ak + 0][am] = av.x;
        As[ak + 1][am] = av.y;
        As[ak + 2][am] = av.z;
        As[ak + 3][am] = av.w;
        *(float4*)&Bs[bk][bn] = bv;
        __syncthreads();
#pragma unroll
        for (int k = 0; k < 16; ++k) {
            float ar[4], br[4];
            *(float4*)ar = *(const float4*)&As[k][ty * 4];
            *(float4*)br = *(const float4*)&Bs[k][tx * 4];
#pragma unroll
            for (int i = 0; i < 4; ++i)
#pragma unroll
                for (int j = 0; j < 4; ++j) acc[i][j] += ar[i] * br[j];
        }
    }

    float bb[4];
    *(float4*)bb = *(const float4*)(bias + n0 + tx * 4);
#pragma unroll
    for (int i = 0; i < 4; ++i) {
        const int m = m0 + ty * 4 + i;
        float4 o;
        o.x = acc[i][0] + bb[0];
        o.y = acc[i][1] + bb[1];
        o.z = acc[i][2] + bb[2];
        o.w = acc[i][3] + bb[3];
        if (RELU) {
            o.x = fmaxf(o.x, 0.f); o.y = fmaxf(o.y, 0.f);
            o.z = fmaxf(o.z, 0.f); o.w = fmaxf(o.w, 0.f);
        }
        *(float4*)(C + (size_t)m * ldc + n0 + tx * 4) = o;
    }
}

// ---------------------------------------------------------------------------
// Size-embedding MLP: 2 -> 64 -> 256 -> 1024, one block per ROI row.
// Writes into right half of xe (ld = 2048, cols 1024..2047).
// ---------------------------------------------------------------------------
__global__ __launch_bounds__(256) void size_mlp(const float* __restrict__ bboxes,
                                                const float* __restrict__ S1,
                                                const float* __restrict__ sb1,
                                                const float* __restrict__ S2,
                                                const float* __restrict__ sb2,
                                                const float* __restrict__ S3,
                                                const float* __restrict__ sb3,
                                                float* __restrict__ xe) {
    const int r = blockIdx.x;
    const int t = threadIdx.x;
    __shared__ float h1[64];
    __shared__ float h2[256];
    const float szh = bboxes[r * 4 + 3] - bboxes[r * 4 + 1];
    const float szw = bboxes[r * 4 + 2] - bboxes[r * 4 + 0];
    if (t < 64) {
        const float v = szh * S1[t] + szw * S1[64 + t] + sb1[t];
        h1[t] = fmaxf(v, 0.0f);
    }
    __syncthreads();
    {
        float acc = sb2[t];
#pragma unroll 8
        for (int k = 0; k < 64; ++k) acc += h1[k] * S2[k * 256 + t];
        h2[t] = fmaxf(acc, 0.0f);
    }
    __syncthreads();
#pragma unroll
    for (int q = 0; q < 4; ++q) {
        const int j = t + q * 256;
        float acc = sb3[j];
#pragma unroll 8
        for (int k = 0; k < 256; ++k) acc += h2[k] * S3[k * 1024 + j];
        xe[(size_t)r * kXE + kOUTC + j] = acc;
    }
}

// ---------------------------------------------------------------------------
extern "C" void kernel_launch(void* const* d_in, const int* in_sizes, int n_in,
                              void* d_out, int out_size, void* d_ws, size_t ws_size,
                              hipStream_t stream) {
    (void)in_sizes; (void)n_in; (void)out_size;
    const float* z   = (const float*)d_in[0];
    const float* bb  = (const float*)d_in[1];
    const float* W1  = (const float*)d_in[2];
    const float* b1  = (const float*)d_in[3];
    const float* W2  = (const float*)d_in[4];
    const float* b2  = (const float*)d_in[5];
    const float* S1  = (const float*)d_in[6];
    const float* sb1 = (const float*)d_in[7];
    const float* S2  = (const float*)d_in[8];
    const float* sb2 = (const float*)d_in[9];
    const float* S3  = (const float*)d_in[10];
    const float* sb3 = (const float*)d_in[11];
    const float* O   = (const float*)d_in[12];
    const float* ob  = (const float*)d_in[13];
    float* out = (float*)d_out;

    char* ws = (char*)d_ws;
    const size_t xBytes  = (size_t)kR * kCH * 4;        //  5.24 MB
    const size_t hBytes  = (size_t)kR * kINNER * 4;     // 20.97 MB
    const size_t xeBytes = (size_t)kR * kXE * 4;        //  8.39 MB
    const size_t ztBytes = (size_t)kBS * kPIX * kCH * 4;// 167.8 MB

    float* x  = (float*)(ws);
    float* h  = (float*)(ws + xBytes);
    float* xe = (float*)(ws + xBytes + hBytes);
    float* zt = (float*)(ws + xBytes + hBytes + xeBytes);
    const bool useT = ws_size >= xBytes + hBytes + xeBytes + ztBytes;

    // 1) ROI-align features -> x (1024 x 1280)
    if (useT) {
        dim3 tg(kPIX / 32, kCH / 32, kBS);
        hipLaunchKernelGGL(transpose_z, tg, dim3(32, 8, 1), 0, stream, z, zt);
        hipLaunchKernelGGL(roi_gather_t, dim3(kR), dim3(256), 0, stream, zt, bb, x);
    } else {
        hipLaunchKernelGGL(roi_gather_direct, dim3(kR), dim3(256), 0, stream, z, bb, x);
    }

    // 2) size-embedding MLP -> xe[:, 1024:2048]
    hipLaunchKernelGGL(size_mlp, dim3(kR), dim3(256), 0, stream,
                       bb, S1, sb1, S2, sb2, S3, sb3, xe);

    // 3) h = relu(x @ W1 + b1)   (1024x1280)@(1280x5120)
    hipLaunchKernelGGL((gemm_f32<true>), dim3(kINNER / 64, kR / 64), dim3(256), 0, stream,
                       x, W1, b1, h, kCH, kCH, kINNER, kINNER);

    // 4) xe[:, 0:1024] = h @ W2 + b2   (1024x5120)@(5120x1024)
    hipLaunchKernelGGL((gemm_f32<false>), dim3(kOUTC / 64, kR / 64), dim3(256), 0, stream,
                       h, W2, b2, xe, kINNER, kINNER, kOUTC, kXE);

    // 5) out = xe @ O + ob   (1024x2048)@(2048x1024)
    hipLaunchKernelGGL((gemm_f32<false>), dim3(kOUTC / 64, kR / 64), dim3(256), 0, stream,
                       xe, O, ob, out, kXE, kXE, kOUTC, kOUTC);
}

// Round 4
// 635.417 us; speedup vs baseline: 1.7824x; 1.7824x over previous
//
#include <hip/hip_runtime.h>

// Problem constants
static constexpr int kBS    = 8;
static constexpr int kNROI  = 128;
static constexpr int kR     = kBS * kNROI;   // 1024 rows
static constexpr int kCH    = 1280;
static constexpr int kH     = 64;
static constexpr int kW     = 64;
static constexpr int kPIX   = kH * kW;       // 4096
static constexpr int kINNER = 5120;
static constexpr int kOUTC  = 1024;
static constexpr int kXE    = 2 * kOUTC;     // 2048 concat width

typedef _Float16 half8 __attribute__((ext_vector_type(8)));   // f16x8 MFMA A/B frag
typedef float floatx4 __attribute__((ext_vector_type(4)));    // MFMA C/D frag

// ---------------------------------------------------------------------------
// Transpose+convert z: (b, c, H*W) fp32 -> zt: (b, H*W, c) f16
// Tile: 64 channels x 32 pixels. Load: 8 iters (64 rows). Write: 4 iters
// (32 pixels), each thread packs 2 adjacent channels into one 4B store.
// (Round-2/3 bug: write loop ran 8 iters -> OOB LDS reads + cross-block
//  races on pixels 32..63. This was the invariant ~1.1 absmax error.)
// ---------------------------------------------------------------------------
__global__ __launch_bounds__(256) void transpose_z_f16(const float* __restrict__ z,
                                                       _Float16* __restrict__ zt) {
    __shared__ float tile[64][33];   // [c_local][p_local]
    const int b  = blockIdx.z;
    const int p0 = blockIdx.x * 32;
    const int c0 = blockIdx.y * 64;
    const int tx = threadIdx.x;      // 0..31
    const int ty = threadIdx.y;      // 0..7
    const float* zb = z + (size_t)b * kCH * kPIX;
    _Float16* ztb = zt + (size_t)b * kPIX * kCH;
#pragma unroll
    for (int i = 0; i < 8; ++i) {
        const int cl = ty + i * 8;   // 0..63
        tile[cl][tx] = zb[(size_t)(c0 + cl) * kPIX + p0 + tx];
    }
    __syncthreads();
#pragma unroll
    for (int i = 0; i < 4; ++i) {
        const int pl = ty + i * 8;   // 0..31
        union { _Float16 h[2]; unsigned int u; } pk;
        pk.h[0] = (_Float16)tile[2 * tx][pl];
        pk.h[1] = (_Float16)tile[2 * tx + 1][pl];
        *(unsigned int*)(ztb + (size_t)(p0 + pl) * kCH + c0 + 2 * tx) = pk.u;
    }
}

// ---------------------------------------------------------------------------
// ROI point lists (separable bilinear weights)
// ---------------------------------------------------------------------------
struct RoiLists {
    int   yidx[16], xidx[16];
    float ywt[16], xwt[16];
    int   ny, nx;
    float invCount;
};

__device__ inline void build_lists(const float* __restrict__ bboxes, int r, RoiLists* L) {
    const float x1 = bboxes[r * 4 + 0] * 0.125f - 0.5f;
    const float y1 = bboxes[r * 4 + 1] * 0.125f - 0.5f;
    const float x2 = bboxes[r * 4 + 2] * 0.125f - 0.5f;
    const float y2 = bboxes[r * 4 + 3] * 0.125f - 0.5f;
    const float rw = x2 - x1, rh = y2 - y1;
    const float gwf = fminf(fmaxf(ceilf(rw), 1.0f), 8.0f);
    const float ghf = fminf(fmaxf(ceilf(rh), 1.0f), 8.0f);
    const int gw = (int)gwf, gh = (int)ghf;
    L->invCount = 1.0f / (gwf * ghf);
    for (int g = 0; g < gh; ++g) {
        const float c   = y1 + ((float)g + 0.5f) * rh / ghf;
        const bool oob  = (c < -1.0f) || (c > 64.0f);
        const float cc  = fmaxf(c, 0.0f);
        const float lo0 = floorf(cc);
        const bool hic  = (lo0 >= 63.0f);
        const int lo    = (int)fminf(lo0, 63.0f);
        const int hi    = (int)fminf(lo0 + 1.0f, 63.0f);
        const float fr  = hic ? 0.0f : (cc - lo0);
        const float m   = oob ? 0.0f : 1.0f;
        L->yidx[2 * g]     = lo; L->ywt[2 * g]     = m * (1.0f - fr);
        L->yidx[2 * g + 1] = hi; L->ywt[2 * g + 1] = m * fr;
    }
    L->ny = 2 * gh;
    for (int g = 0; g < gw; ++g) {
        const float c   = x1 + ((float)g + 0.5f) * rw / gwf;
        const bool oob  = (c < -1.0f) || (c > 64.0f);
        const float cc  = fmaxf(c, 0.0f);
        const float lo0 = floorf(cc);
        const bool hic  = (lo0 >= 63.0f);
        const int lo    = (int)fminf(lo0, 63.0f);
        const int hi    = (int)fminf(lo0 + 1.0f, 63.0f);
        const float fr  = hic ? 0.0f : (cc - lo0);
        const float m   = oob ? 0.0f : 1.0f;
        L->xidx[2 * g]     = lo; L->xwt[2 * g]     = m * (1.0f - fr);
        L->xidx[2 * g + 1] = hi; L->xwt[2 * g + 1] = m * fr;
    }
    L->nx = 2 * gw;
}

// Gather from channels-last f16 zt -> f16 x (1024 x 1280)
__global__ __launch_bounds__(256) void roi_gather_f16(const _Float16* __restrict__ zt,
                                                      const float* __restrict__ bboxes,
                                                      _Float16* __restrict__ x) {
    const int r = blockIdx.x;
    const int b = r >> 7;
    __shared__ RoiLists L;
    if (threadIdx.x == 0) build_lists(bboxes, r, &L);
    __syncthreads();
    const int ny = L.ny, nx = L.nx;
    const float ic = L.invCount;
    const _Float16* ztb = zt + (size_t)b * kPIX * kCH;
    for (int c8 = threadIdx.x; c8 < kCH / 8; c8 += 256) {
        float acc[8] = {0.f, 0.f, 0.f, 0.f, 0.f, 0.f, 0.f, 0.f};
        for (int iy = 0; iy < ny; ++iy) {
            const float wy = L.ywt[iy];
            const int Yb   = L.yidx[iy] * kW;
            for (int ix = 0; ix < nx; ++ix) {
                const float w = wy * L.xwt[ix];
                const half8 v = *(const half8*)(ztb + (size_t)(Yb + L.xidx[ix]) * kCH + c8 * 8);
#pragma unroll
                for (int q = 0; q < 8; ++q) acc[q] += w * (float)v[q];
            }
        }
        half8 o;
#pragma unroll
        for (int q = 0; q < 8; ++q) o[q] = (_Float16)(acc[q] * ic);
        *(half8*)&x[(size_t)r * kCH + c8 * 8] = o;
    }
}

// Fallback: gather directly from fp32 z (b,c,H,W) -> f16 x
__global__ __launch_bounds__(256) void roi_gather_direct(const float* __restrict__ z,
                                                         const float* __restrict__ bboxes,
                                                         _Float16* __restrict__ x) {
    const int r = blockIdx.x;
    const int b = r >> 7;
    __shared__ RoiLists L;
    if (threadIdx.x == 0) build_lists(bboxes, r, &L);
    __syncthreads();
    const int ny = L.ny, nx = L.nx;
    const float ic = L.invCount;
    const float* zb = z + (size_t)b * kCH * kPIX;
    for (int c = threadIdx.x; c < kCH; c += 256) {
        const float* zc = zb + (size_t)c * kPIX;
        float acc = 0.f;
        for (int iy = 0; iy < ny; ++iy) {
            const float wy = L.ywt[iy];
            const int base = L.yidx[iy] * kW;
            for (int ix = 0; ix < nx; ++ix)
                acc += wy * L.xwt[ix] * zc[base + L.xidx[ix]];
        }
        x[(size_t)r * kCH + c] = (_Float16)(acc * ic);
    }
}

// ---------------------------------------------------------------------------
// Weight transpose+convert: W (K x N) fp32 -> Wt (N x K) f16
// ---------------------------------------------------------------------------
__global__ __launch_bounds__(256) void convert_transpose(const float* __restrict__ W,
                                                         _Float16* __restrict__ Wt,
                                                         int K, int N) {
    __shared__ float tile[32][33];  // [k][n]
    const int n0 = blockIdx.x * 32;
    const int k0 = blockIdx.y * 32;
    const int tx = threadIdx.x;     // 0..31
    const int ty = threadIdx.y;     // 0..7
#pragma unroll
    for (int i = 0; i < 4; ++i)
        tile[ty + i * 8][tx] = W[(size_t)(k0 + ty + i * 8) * N + n0 + tx];
    __syncthreads();
#pragma unroll
    for (int i = 0; i < 4; ++i)
        Wt[(size_t)(n0 + ty + i * 8) * K + k0 + tx] = (_Float16)tile[tx][ty + i * 8];
}

// ---------------------------------------------------------------------------
// f16 MFMA GEMM (NT): C(MxN) = op(A(MxK) @ Bt(NxK)^T + bias)
// 128x128 tile, BK=32, 256 threads = 4 waves, each wave 4x4 tiles of 16x16x32.
// lda = ldb = K (row-major, K-contiguous).
// ---------------------------------------------------------------------------
template <bool RELU, bool F16OUT>
__global__ __launch_bounds__(256) void gemm_f16(const _Float16* __restrict__ A,
                                                const _Float16* __restrict__ Bt,
                                                const float* __restrict__ bias,
                                                void* __restrict__ Cout,
                                                int K, int ldc) {
    __shared__ _Float16 As[128 * 32];   // [m][k] row-major
    __shared__ _Float16 Bs[128 * 32];   // [n][k] row-major
    const int t    = threadIdx.x;
    const int lane = t & 63;
    const int wave = t >> 6;
    const int m0 = blockIdx.y * 128, n0 = blockIdx.x * 128;

    // Staging: 512 16B chunks per tile; each thread stages 2 chunks of A and B.
    const int c0 = t, c1 = t + 256;
    const _Float16* Ag0 = A + (size_t)(m0 + (c0 >> 2)) * K + (c0 & 3) * 8;
    const _Float16* Ag1 = A + (size_t)(m0 + (c1 >> 2)) * K + (c1 & 3) * 8;
    const _Float16* Bg0 = Bt + (size_t)(n0 + (c0 >> 2)) * K + (c0 & 3) * 8;
    const _Float16* Bg1 = Bt + (size_t)(n0 + (c1 >> 2)) * K + (c1 & 3) * 8;

    const int wm = (wave >> 1) * 64;       // wave row offset in tile
    const int wn = (wave & 1) * 64;        // wave col offset in tile
    const int fm = lane & 15;              // fragment row/col within 16
    const int kq = (lane >> 4) * 8;        // fragment k offset

    floatx4 acc[4][4];
#pragma unroll
    for (int i = 0; i < 4; ++i)
#pragma unroll
        for (int j = 0; j < 4; ++j) acc[i][j] = (floatx4){0.f, 0.f, 0.f, 0.f};

    uint4 pa0 = *(const uint4*)(Ag0);
    uint4 pa1 = *(const uint4*)(Ag1);
    uint4 pb0 = *(const uint4*)(Bg0);
    uint4 pb1 = *(const uint4*)(Bg1);

    for (int k0i = 0; k0i < K; k0i += 32) {
        __syncthreads();
        *(uint4*)&As[c0 * 8] = pa0;
        *(uint4*)&As[c1 * 8] = pa1;
        *(uint4*)&Bs[c0 * 8] = pb0;
        *(uint4*)&Bs[c1 * 8] = pb1;
        __syncthreads();

        const int kn = (k0i + 32 < K) ? (k0i + 32) : k0i;   // safe dummy refetch on last iter
        pa0 = *(const uint4*)(Ag0 + kn);
        pa1 = *(const uint4*)(Ag1 + kn);
        pb0 = *(const uint4*)(Bg0 + kn);
        pb1 = *(const uint4*)(Bg1 + kn);

        half8 af[4], bfv[4];
#pragma unroll
        for (int i = 0; i < 4; ++i)
            af[i] = *(const half8*)&As[(wm + i * 16 + fm) * 32 + kq];
#pragma unroll
        for (int j = 0; j < 4; ++j)
            bfv[j] = *(const half8*)&Bs[(wn + j * 16 + fm) * 32 + kq];
#pragma unroll
        for (int i = 0; i < 4; ++i)
#pragma unroll
            for (int j = 0; j < 4; ++j)
                acc[i][j] = __builtin_amdgcn_mfma_f32_16x16x32_f16(af[i], bfv[j], acc[i][j], 0, 0, 0);
    }

    // Epilogue: C/D layout col = lane&15, row = (lane>>4)*4 + r
    const int qr = (lane >> 4) * 4;
#pragma unroll
    for (int j = 0; j < 4; ++j) {
        const int col = n0 + wn + j * 16 + fm;
        const float bj = bias[col];
#pragma unroll
        for (int i = 0; i < 4; ++i) {
            const int row = m0 + wm + i * 16 + qr;
#pragma unroll
            for (int rr = 0; rr < 4; ++rr) {
                float v = acc[i][j][rr] + bj;
                if (RELU) v = fmaxf(v, 0.f);
                if (F16OUT)
                    ((_Float16*)Cout)[(size_t)(row + rr) * ldc + col] = (_Float16)v;
                else
                    ((float*)Cout)[(size_t)(row + rr) * ldc + col] = v;
            }
        }
    }
}

// ---------------------------------------------------------------------------
// Size-embedding MLP: 2 -> 64 -> 256 -> 1024, one block per ROI row.
// Writes f16 into right half of xe (ld = 2048, cols 1024..2047).
// ---------------------------------------------------------------------------
__global__ __launch_bounds__(256) void size_mlp(const float* __restrict__ bboxes,
                                                const float* __restrict__ S1,
                                                const float* __restrict__ sb1,
                                                const float* __restrict__ S2,
                                                const float* __restrict__ sb2,
                                                const float* __restrict__ S3,
                                                const float* __restrict__ sb3,
                                                _Float16* __restrict__ xe) {
    const int r = blockIdx.x;
    const int t = threadIdx.x;
    __shared__ float h1[64];
    __shared__ float h2[256];
    const float szh = bboxes[r * 4 + 3] - bboxes[r * 4 + 1];
    const float szw = bboxes[r * 4 + 2] - bboxes[r * 4 + 0];
    if (t < 64) {
        const float v = szh * S1[t] + szw * S1[64 + t] + sb1[t];
        h1[t] = fmaxf(v, 0.0f);
    }
    __syncthreads();
    {
        float acc = sb2[t];
#pragma unroll 8
        for (int k = 0; k < 64; ++k) acc += h1[k] * S2[k * 256 + t];
        h2[t] = fmaxf(acc, 0.0f);
    }
    __syncthreads();
#pragma unroll
    for (int q = 0; q < 4; ++q) {
        const int j = t + q * 256;
        float acc = sb3[j];
#pragma unroll 8
        for (int k = 0; k < 256; ++k) acc += h2[k] * S3[k * 1024 + j];
        xe[(size_t)r * kXE + kOUTC + j] = (_Float16)acc;
    }
}

// ---------------------------------------------------------------------------
extern "C" void kernel_launch(void* const* d_in, const int* in_sizes, int n_in,
                              void* d_out, int out_size, void* d_ws, size_t ws_size,
                              hipStream_t stream) {
    (void)in_sizes; (void)n_in; (void)out_size;
    const float* z   = (const float*)d_in[0];
    const float* bb  = (const float*)d_in[1];
    const float* W1  = (const float*)d_in[2];
    const float* b1  = (const float*)d_in[3];
    const float* W2  = (const float*)d_in[4];
    const float* b2  = (const float*)d_in[5];
    const float* S1  = (const float*)d_in[6];
    const float* sb1 = (const float*)d_in[7];
    const float* S2  = (const float*)d_in[8];
    const float* sb2 = (const float*)d_in[9];
    const float* S3  = (const float*)d_in[10];
    const float* sb3 = (const float*)d_in[11];
    const float* O   = (const float*)d_in[12];
    const float* ob  = (const float*)d_in[13];
    float* out = (float*)d_out;

    char* ws = (char*)d_ws;
    size_t off = 0;
    auto alloc = [&](size_t bytes) {
        void* p = ws + off;
        off += (bytes + 255) & ~(size_t)255;
        return p;
    };
    _Float16* x   = (_Float16*)alloc((size_t)kR * kCH * 2);       //  2.6 MB
    _Float16* h   = (_Float16*)alloc((size_t)kR * kINNER * 2);    // 10.5 MB
    _Float16* xe  = (_Float16*)alloc((size_t)kR * kXE * 2);       //  4.2 MB
    _Float16* W1t = (_Float16*)alloc((size_t)kINNER * kCH * 2);   // 13.1 MB
    _Float16* W2t = (_Float16*)alloc((size_t)kOUTC * kINNER * 2); // 10.5 MB
    _Float16* Ot  = (_Float16*)alloc((size_t)kOUTC * kXE * 2);    //  4.2 MB
    const size_t ztBytes = (size_t)kBS * kPIX * kCH * 2;          // 83.9 MB
    _Float16* zt  = (_Float16*)(ws + off);
    const bool useT = (off + ztBytes) <= ws_size;

    // Weight conversions (fp32 -> f16, transposed to N x K)
    hipLaunchKernelGGL(convert_transpose, dim3(kINNER / 32, kCH / 32), dim3(32, 8), 0, stream,
                       W1, W1t, kCH, kINNER);
    hipLaunchKernelGGL(convert_transpose, dim3(kOUTC / 32, kINNER / 32), dim3(32, 8), 0, stream,
                       W2, W2t, kINNER, kOUTC);
    hipLaunchKernelGGL(convert_transpose, dim3(kOUTC / 32, kXE / 32), dim3(32, 8), 0, stream,
                       O, Ot, kXE, kOUTC);

    // 1) ROI-align features -> x (1024 x 1280 f16)
    if (useT) {
        hipLaunchKernelGGL(transpose_z_f16, dim3(kPIX / 32, kCH / 64, kBS), dim3(32, 8), 0,
                           stream, z, zt);
        hipLaunchKernelGGL(roi_gather_f16, dim3(kR), dim3(256), 0, stream, zt, bb, x);
    } else {
        hipLaunchKernelGGL(roi_gather_direct, dim3(kR), dim3(256), 0, stream, z, bb, x);
    }

    // 2) size-embedding MLP -> xe[:, 1024:2048] (f16)
    hipLaunchKernelGGL(size_mlp, dim3(kR), dim3(256), 0, stream,
                       bb, S1, sb1, S2, sb2, S3, sb3, xe);

    // 3) h = relu(x @ W1 + b1)   (1024x1280)@(1280x5120) -> f16
    hipLaunchKernelGGL((gemm_f16<true, true>), dim3(kINNER / 128, kR / 128), dim3(256), 0,
                       stream, x, W1t, b1, h, kCH, kINNER);

    // 4) xe[:, 0:1024] = h @ W2 + b2   (1024x5120)@(5120x1024) -> f16
    hipLaunchKernelGGL((gemm_f16<false, true>), dim3(kOUTC / 128, kR / 128), dim3(256), 0,
                       stream, h, W2t, b2, xe, kINNER, kXE);

    // 5) out = xe @ O + ob   (1024x2048)@(2048x1024) -> fp32
    hipLaunchKernelGGL((gemm_f16<false, false>), dim3(kOUTC / 128, kR / 128), dim3(256), 0,
                       stream, xe, Ot, ob, out, kXE, kOUTC);
}

// Round 5
// 518.556 us; speedup vs baseline: 2.1841x; 1.2254x over previous
//
#include <hip/hip_runtime.h>

// Problem constants
static constexpr int kBS    = 8;
static constexpr int kNROI  = 128;
static constexpr int kR     = kBS * kNROI;   // 1024 rows
static constexpr int kCH    = 1280;
static constexpr int kH     = 64;
static constexpr int kW     = 64;
static constexpr int kPIX   = kH * kW;       // 4096
static constexpr int kINNER = 5120;
static constexpr int kOUTC  = 1024;
static constexpr int kXE    = 2 * kOUTC;     // 2048 concat width

typedef _Float16 half8 __attribute__((ext_vector_type(8)));   // f16x8 MFMA A/B frag
typedef float floatx4 __attribute__((ext_vector_type(4)));    // MFMA C/D frag

// ---------------------------------------------------------------------------
// Transpose+convert z: (b, c, H*W) fp32 -> zt: (b, H*W, c) f16
// Tile: 64 channels x 32 pixels. Load: 8 iters. Write: 4 iters (32 pixels),
// each thread packs 2 adjacent channels into one 4B store.
// ---------------------------------------------------------------------------
__global__ __launch_bounds__(256) void transpose_z_f16(const float* __restrict__ z,
                                                       _Float16* __restrict__ zt) {
    __shared__ float tile[64][33];   // [c_local][p_local]
    const int b  = blockIdx.z;
    const int p0 = blockIdx.x * 32;
    const int c0 = blockIdx.y * 64;
    const int tx = threadIdx.x;      // 0..31
    const int ty = threadIdx.y;      // 0..7
    const float* zb = z + (size_t)b * kCH * kPIX;
    _Float16* ztb = zt + (size_t)b * kPIX * kCH;
#pragma unroll
    for (int i = 0; i < 8; ++i) {
        const int cl = ty + i * 8;   // 0..63
        tile[cl][tx] = zb[(size_t)(c0 + cl) * kPIX + p0 + tx];
    }
    __syncthreads();
#pragma unroll
    for (int i = 0; i < 4; ++i) {
        const int pl = ty + i * 8;   // 0..31
        union { _Float16 h[2]; unsigned int u; } pk;
        pk.h[0] = (_Float16)tile[2 * tx][pl];
        pk.h[1] = (_Float16)tile[2 * tx + 1][pl];
        *(unsigned int*)(ztb + (size_t)(p0 + pl) * kCH + c0 + 2 * tx) = pk.u;
    }
}

// ---------------------------------------------------------------------------
// ROI point lists (separable bilinear weights)
// ---------------------------------------------------------------------------
struct RoiLists {
    int   yidx[16], xidx[16];
    float ywt[16], xwt[16];
    int   ny, nx;
    float invCount;
};

__device__ inline void build_lists(const float* __restrict__ bboxes, int r, RoiLists* L) {
    const float x1 = bboxes[r * 4 + 0] * 0.125f - 0.5f;
    const float y1 = bboxes[r * 4 + 1] * 0.125f - 0.5f;
    const float x2 = bboxes[r * 4 + 2] * 0.125f - 0.5f;
    const float y2 = bboxes[r * 4 + 3] * 0.125f - 0.5f;
    const float rw = x2 - x1, rh = y2 - y1;
    const float gwf = fminf(fmaxf(ceilf(rw), 1.0f), 8.0f);
    const float ghf = fminf(fmaxf(ceilf(rh), 1.0f), 8.0f);
    const int gw = (int)gwf, gh = (int)ghf;
    L->invCount = 1.0f / (gwf * ghf);
    for (int g = 0; g < gh; ++g) {
        const float c   = y1 + ((float)g + 0.5f) * rh / ghf;
        const bool oob  = (c < -1.0f) || (c > 64.0f);
        const float cc  = fmaxf(c, 0.0f);
        const float lo0 = floorf(cc);
        const bool hic  = (lo0 >= 63.0f);
        const int lo    = (int)fminf(lo0, 63.0f);
        const int hi    = (int)fminf(lo0 + 1.0f, 63.0f);
        const float fr  = hic ? 0.0f : (cc - lo0);
        const float m   = oob ? 0.0f : 1.0f;
        L->yidx[2 * g]     = lo; L->ywt[2 * g]     = m * (1.0f - fr);
        L->yidx[2 * g + 1] = hi; L->ywt[2 * g + 1] = m * fr;
    }
    L->ny = 2 * gh;
    for (int g = 0; g < gw; ++g) {
        const float c   = x1 + ((float)g + 0.5f) * rw / gwf;
        const bool oob  = (c < -1.0f) || (c > 64.0f);
        const float cc  = fmaxf(c, 0.0f);
        const float lo0 = floorf(cc);
        const bool hic  = (lo0 >= 63.0f);
        const int lo    = (int)fminf(lo0, 63.0f);
        const int hi    = (int)fminf(lo0 + 1.0f, 63.0f);
        const float fr  = hic ? 0.0f : (cc - lo0);
        const float m   = oob ? 0.0f : 1.0f;
        L->xidx[2 * g]     = lo; L->xwt[2 * g]     = m * (1.0f - fr);
        L->xidx[2 * g + 1] = hi; L->xwt[2 * g + 1] = m * fr;
    }
    L->nx = 2 * gw;
}

// Gather from channels-last f16 zt -> f16 x (1024 x 1280)
__global__ __launch_bounds__(256) void roi_gather_f16(const _Float16* __restrict__ zt,
                                                      const float* __restrict__ bboxes,
                                                      _Float16* __restrict__ x) {
    const int r = blockIdx.x;
    const int b = r >> 7;
    __shared__ RoiLists L;
    if (threadIdx.x == 0) build_lists(bboxes, r, &L);
    __syncthreads();
    const int ny = L.ny, nx = L.nx;
    const float ic = L.invCount;
    const _Float16* ztb = zt + (size_t)b * kPIX * kCH;
    for (int c8 = threadIdx.x; c8 < kCH / 8; c8 += 256) {
        float acc[8] = {0.f, 0.f, 0.f, 0.f, 0.f, 0.f, 0.f, 0.f};
        for (int iy = 0; iy < ny; ++iy) {
            const float wy = L.ywt[iy];
            const int Yb   = L.yidx[iy] * kW;
            for (int ix = 0; ix < nx; ++ix) {
                const float w = wy * L.xwt[ix];
                const half8 v = *(const half8*)(ztb + (size_t)(Yb + L.xidx[ix]) * kCH + c8 * 8);
#pragma unroll
                for (int q = 0; q < 8; ++q) acc[q] += w * (float)v[q];
            }
        }
        half8 o;
#pragma unroll
        for (int q = 0; q < 8; ++q) o[q] = (_Float16)(acc[q] * ic);
        *(half8*)&x[(size_t)r * kCH + c8 * 8] = o;
    }
}

// Fallback: gather directly from fp32 z (b,c,H,W) -> f16 x
__global__ __launch_bounds__(256) void roi_gather_direct(const float* __restrict__ z,
                                                         const float* __restrict__ bboxes,
                                                         _Float16* __restrict__ x) {
    const int r = blockIdx.x;
    const int b = r >> 7;
    __shared__ RoiLists L;
    if (threadIdx.x == 0) build_lists(bboxes, r, &L);
    __syncthreads();
    const int ny = L.ny, nx = L.nx;
    const float ic = L.invCount;
    const float* zb = z + (size_t)b * kCH * kPIX;
    for (int c = threadIdx.x; c < kCH; c += 256) {
        const float* zc = zb + (size_t)c * kPIX;
        float acc = 0.f;
        for (int iy = 0; iy < ny; ++iy) {
            const float wy = L.ywt[iy];
            const int base = L.yidx[iy] * kW;
            for (int ix = 0; ix < nx; ++ix)
                acc += wy * L.xwt[ix] * zc[base + L.xidx[ix]];
        }
        x[(size_t)r * kCH + c] = (_Float16)(acc * ic);
    }
}

// ---------------------------------------------------------------------------
// Weight transpose+convert: W (K x N) fp32 -> Wt (N x K) f16
// ---------------------------------------------------------------------------
__global__ __launch_bounds__(256) void convert_transpose(const float* __restrict__ W,
                                                         _Float16* __restrict__ Wt,
                                                         int K, int N) {
    __shared__ float tile[32][33];  // [k][n]
    const int n0 = blockIdx.x * 32;
    const int k0 = blockIdx.y * 32;
    const int tx = threadIdx.x;     // 0..31
    const int ty = threadIdx.y;     // 0..7
#pragma unroll
    for (int i = 0; i < 4; ++i)
        tile[ty + i * 8][tx] = W[(size_t)(k0 + ty + i * 8) * N + n0 + tx];
    __syncthreads();
#pragma unroll
    for (int i = 0; i < 4; ++i)
        Wt[(size_t)(n0 + ty + i * 8) * K + k0 + tx] = (_Float16)tile[tx][ty + i * 8];
}

// ---------------------------------------------------------------------------
// Split-K f16 MFMA GEMM (NT): P[s] = A[:, s*Ks:(s+1)*Ks] @ Bt[:, same]^T
// 128x128 tile, BK=32, 256 threads = 4 waves, each wave 4x4 tiles of 16x16x32.
// A: M x Kfull (row stride Kfull), Bt: N x Kfull. Partials fp32, dense N.
// blockIdx.z = split index. Every (s,m,n) is written -> no init needed.
// ---------------------------------------------------------------------------
template <int NSPLIT>
__global__ __launch_bounds__(256) void gemm_f16_sk(const _Float16* __restrict__ A,
                                                   const _Float16* __restrict__ Bt,
                                                   float* __restrict__ P,
                                                   int Kfull) {
    __shared__ _Float16 As[128 * 32];   // [m][k] row-major
    __shared__ _Float16 Bs[128 * 32];   // [n][k] row-major
    const int t    = threadIdx.x;
    const int lane = t & 63;
    const int wave = t >> 6;
    const int m0 = blockIdx.y * 128, n0 = blockIdx.x * 128;
    const int Ksplit = Kfull / NSPLIT;
    const int s  = blockIdx.z;
    const int Nn = gridDim.x * 128;
    const int Mm = gridDim.y * 128;
    float* Pp = P + (size_t)s * Mm * Nn;

    // Staging: 512 16B chunks per tile; each thread stages 2 chunks of A and B.
    const int c0 = t, c1 = t + 256;
    const _Float16* Ag0 = A + (size_t)(m0 + (c0 >> 2)) * Kfull + (c0 & 3) * 8 + s * Ksplit;
    const _Float16* Ag1 = A + (size_t)(m0 + (c1 >> 2)) * Kfull + (c1 & 3) * 8 + s * Ksplit;
    const _Float16* Bg0 = Bt + (size_t)(n0 + (c0 >> 2)) * Kfull + (c0 & 3) * 8 + s * Ksplit;
    const _Float16* Bg1 = Bt + (size_t)(n0 + (c1 >> 2)) * Kfull + (c1 & 3) * 8 + s * Ksplit;

    const int wm = (wave >> 1) * 64;       // wave row offset in tile
    const int wn = (wave & 1) * 64;        // wave col offset in tile
    const int fm = lane & 15;              // fragment row/col within 16
    const int kq = (lane >> 4) * 8;        // fragment k offset

    floatx4 acc[4][4];
#pragma unroll
    for (int i = 0; i < 4; ++i)
#pragma unroll
        for (int j = 0; j < 4; ++j) acc[i][j] = (floatx4){0.f, 0.f, 0.f, 0.f};

    uint4 pa0 = *(const uint4*)(Ag0);
    uint4 pa1 = *(const uint4*)(Ag1);
    uint4 pb0 = *(const uint4*)(Bg0);
    uint4 pb1 = *(const uint4*)(Bg1);

    for (int k0i = 0; k0i < Ksplit; k0i += 32) {
        __syncthreads();
        *(uint4*)&As[c0 * 8] = pa0;
        *(uint4*)&As[c1 * 8] = pa1;
        *(uint4*)&Bs[c0 * 8] = pb0;
        *(uint4*)&Bs[c1 * 8] = pb1;
        __syncthreads();

        const int kn = (k0i + 32 < Ksplit) ? (k0i + 32) : k0i;  // safe dummy refetch
        pa0 = *(const uint4*)(Ag0 + kn);
        pa1 = *(const uint4*)(Ag1 + kn);
        pb0 = *(const uint4*)(Bg0 + kn);
        pb1 = *(const uint4*)(Bg1 + kn);

        half8 af[4], bfv[4];
#pragma unroll
        for (int i = 0; i < 4; ++i)
            af[i] = *(const half8*)&As[(wm + i * 16 + fm) * 32 + kq];
#pragma unroll
        for (int j = 0; j < 4; ++j)
            bfv[j] = *(const half8*)&Bs[(wn + j * 16 + fm) * 32 + kq];
#pragma unroll
        for (int i = 0; i < 4; ++i)
#pragma unroll
            for (int j = 0; j < 4; ++j)
                acc[i][j] = __builtin_amdgcn_mfma_f32_16x16x32_f16(af[i], bfv[j], acc[i][j], 0, 0, 0);
    }

    // Epilogue: raw fp32 partial store. C/D layout col = lane&15, row = (lane>>4)*4 + rr
    const int qr = (lane >> 4) * 4;
#pragma unroll
    for (int j = 0; j < 4; ++j) {
        const int col = n0 + wn + j * 16 + fm;
#pragma unroll
        for (int i = 0; i < 4; ++i) {
            const int row = m0 + wm + i * 16 + qr;
#pragma unroll
            for (int rr = 0; rr < 4; ++rr)
                Pp[(size_t)(row + rr) * Nn + col] = acc[i][j][rr];
        }
    }
}

// ---------------------------------------------------------------------------
// Split-K reduce + bias + (relu) + convert. Grid covers M*Nn/1024 blocks;
// each thread handles 4 contiguous n. P planes are dense (ld = Nn); output
// can have a different ldc (for writing into the xe concat buffer).
// ---------------------------------------------------------------------------
template <bool RELU, bool F16OUT, int NSPLIT>
__global__ __launch_bounds__(256) void reduce_splitk(const float* __restrict__ P,
                                                     const float* __restrict__ bias,
                                                     void* __restrict__ Cout,
                                                     int Nn, int ldc) {
    const size_t idx = ((size_t)blockIdx.x * 256 + threadIdx.x) * 4;
    const size_t MN  = (size_t)gridDim.x * 1024;
    const int m = (int)(idx / (size_t)Nn);
    const int n = (int)(idx % (size_t)Nn);
    float4 acc = *(const float4*)(P + idx);
#pragma unroll
    for (int s = 1; s < NSPLIT; ++s) {
        const float4 v = *(const float4*)(P + (size_t)s * MN + idx);
        acc.x += v.x; acc.y += v.y; acc.z += v.z; acc.w += v.w;
    }
    const float4 b4 = *(const float4*)(bias + n);
    acc.x += b4.x; acc.y += b4.y; acc.z += b4.z; acc.w += b4.w;
    if (RELU) {
        acc.x = fmaxf(acc.x, 0.f); acc.y = fmaxf(acc.y, 0.f);
        acc.z = fmaxf(acc.z, 0.f); acc.w = fmaxf(acc.w, 0.f);
    }
    if (F16OUT) {
        union { _Float16 h[4]; uint2 u; } pk;
        pk.h[0] = (_Float16)acc.x; pk.h[1] = (_Float16)acc.y;
        pk.h[2] = (_Float16)acc.z; pk.h[3] = (_Float16)acc.w;
        *(uint2*)((_Float16*)Cout + (size_t)m * ldc + n) = pk.u;
    } else {
        *(float4*)((float*)Cout + (size_t)m * ldc + n) = acc;
    }
}

// ---------------------------------------------------------------------------
// Size-embedding MLP: 2 -> 64 -> 256 -> 1024, one block per ROI row.
// Writes f16 into right half of xe (ld = 2048, cols 1024..2047).
// ---------------------------------------------------------------------------
__global__ __launch_bounds__(256) void size_mlp(const float* __restrict__ bboxes,
                                                const float* __restrict__ S1,
                                                const float* __restrict__ sb1,
                                                const float* __restrict__ S2,
                                                const float* __restrict__ sb2,
                                                const float* __restrict__ S3,
                                                const float* __restrict__ sb3,
                                                _Float16* __restrict__ xe) {
    const int r = blockIdx.x;
    const int t = threadIdx.x;
    __shared__ float h1[64];
    __shared__ float h2[256];
    const float szh = bboxes[r * 4 + 3] - bboxes[r * 4 + 1];
    const float szw = bboxes[r * 4 + 2] - bboxes[r * 4 + 0];
    if (t < 64) {
        const float v = szh * S1[t] + szw * S1[64 + t] + sb1[t];
        h1[t] = fmaxf(v, 0.0f);
    }
    __syncthreads();
    {
        float acc = sb2[t];
#pragma unroll 8
        for (int k = 0; k < 64; ++k) acc += h1[k] * S2[k * 256 + t];
        h2[t] = fmaxf(acc, 0.0f);
    }
    __syncthreads();
#pragma unroll
    for (int q = 0; q < 4; ++q) {
        const int j = t + q * 256;
        float acc = sb3[j];
#pragma unroll 8
        for (int k = 0; k < 256; ++k) acc += h2[k] * S3[k * 1024 + j];
        xe[(size_t)r * kXE + kOUTC + j] = (_Float16)acc;
    }
}

// ---------------------------------------------------------------------------
extern "C" void kernel_launch(void* const* d_in, const int* in_sizes, int n_in,
                              void* d_out, int out_size, void* d_ws, size_t ws_size,
                              hipStream_t stream) {
    (void)in_sizes; (void)n_in; (void)out_size;
    const float* z   = (const float*)d_in[0];
    const float* bb  = (const float*)d_in[1];
    const float* W1  = (const float*)d_in[2];
    const float* b1  = (const float*)d_in[3];
    const float* W2  = (const float*)d_in[4];
    const float* b2  = (const float*)d_in[5];
    const float* S1  = (const float*)d_in[6];
    const float* sb1 = (const float*)d_in[7];
    const float* S2  = (const float*)d_in[8];
    const float* sb2 = (const float*)d_in[9];
    const float* S3  = (const float*)d_in[10];
    const float* sb3 = (const float*)d_in[11];
    const float* O   = (const float*)d_in[12];
    const float* ob  = (const float*)d_in[13];
    float* out = (float*)d_out;

    char* ws = (char*)d_ws;
    size_t off = 0;
    auto alloc = [&](size_t bytes) {
        void* p = ws + off;
        off += (bytes + 255) & ~(size_t)255;
        return p;
    };
    _Float16* x   = (_Float16*)alloc((size_t)kR * kCH * 2);       //  2.6 MB
    _Float16* h   = (_Float16*)alloc((size_t)kR * kINNER * 2);    // 10.5 MB
    _Float16* xe  = (_Float16*)alloc((size_t)kR * kXE * 2);       //  4.2 MB
    _Float16* W1t = (_Float16*)alloc((size_t)kINNER * kCH * 2);   // 13.1 MB
    _Float16* W2t = (_Float16*)alloc((size_t)kOUTC * kINNER * 2); // 10.5 MB
    _Float16* Ot  = (_Float16*)alloc((size_t)kOUTC * kXE * 2);    //  4.2 MB
    float*    P   = (float*)alloc((size_t)2 * kR * kINNER * 4);   // 41.9 MB (max partials)
    const size_t ztBytes = (size_t)kBS * kPIX * kCH * 2;          // 83.9 MB
    _Float16* zt  = (_Float16*)(ws + off);
    const bool useT = (off + ztBytes) <= ws_size;

    // Weight conversions (fp32 -> f16, transposed to N x K)
    hipLaunchKernelGGL(convert_transpose, dim3(kINNER / 32, kCH / 32), dim3(32, 8), 0, stream,
                       W1, W1t, kCH, kINNER);
    hipLaunchKernelGGL(convert_transpose, dim3(kOUTC / 32, kINNER / 32), dim3(32, 8), 0, stream,
                       W2, W2t, kINNER, kOUTC);
    hipLaunchKernelGGL(convert_transpose, dim3(kOUTC / 32, kXE / 32), dim3(32, 8), 0, stream,
                       O, Ot, kXE, kOUTC);

    // 1) ROI-align features -> x (1024 x 1280 f16)
    if (useT) {
        hipLaunchKernelGGL(transpose_z_f16, dim3(kPIX / 32, kCH / 64, kBS), dim3(32, 8), 0,
                           stream, z, zt);
        hipLaunchKernelGGL(roi_gather_f16, dim3(kR), dim3(256), 0, stream, zt, bb, x);
    } else {
        hipLaunchKernelGGL(roi_gather_direct, dim3(kR), dim3(256), 0, stream, z, bb, x);
    }

    // 2) size-embedding MLP -> xe[:, 1024:2048] (f16)
    hipLaunchKernelGGL(size_mlp, dim3(kR), dim3(256), 0, stream,
                       bb, S1, sb1, S2, sb2, S3, sb3, xe);

    // 3) h = relu(x @ W1 + b1)   (1024x1280)@(1280x5120), split-K x2 -> f16
    hipLaunchKernelGGL((gemm_f16_sk<2>), dim3(kINNER / 128, kR / 128, 2), dim3(256), 0,
                       stream, x, W1t, P, kCH);
    hipLaunchKernelGGL((reduce_splitk<true, true, 2>),
                       dim3((size_t)kR * kINNER / 1024), dim3(256), 0, stream,
                       P, b1, h, kINNER, kINNER);

    // 4) xe[:, 0:1024] = h @ W2 + b2   (1024x5120)@(5120x1024), split-K x8 -> f16
    hipLaunchKernelGGL((gemm_f16_sk<8>), dim3(kOUTC / 128, kR / 128, 8), dim3(256), 0,
                       stream, h, W2t, P, kINNER);
    hipLaunchKernelGGL((reduce_splitk<false, true, 8>),
                       dim3((size_t)kR * kOUTC / 1024), dim3(256), 0, stream,
                       P, b2, xe, kOUTC, kXE);

    // 5) out = xe @ O + ob   (1024x2048)@(2048x1024), split-K x4 -> fp32
    hipLaunchKernelGGL((gemm_f16_sk<4>), dim3(kOUTC / 128, kR / 128, 4), dim3(256), 0,
                       stream, xe, Ot, P, kXE);
    hipLaunchKernelGGL((reduce_splitk<false, false, 4>),
                       dim3((size_t)kR * kOUTC / 1024), dim3(256), 0, stream,
                       P, ob, out, kOUTC, kOUTC);
}